// Round 5
// baseline (635.555 us; speedup 1.0000x reference)
//
#include <hip/hip_runtime.h>
#include <math.h>

// Problem constants (B=4, C=64, H=160, W=320)
#define HH 160
#define WW 320
#define HWP (HH * WW)   // 51200

typedef __attribute__((ext_vector_type(4))) float f32x4;
typedef __attribute__((ext_vector_type(8))) short s16x8;
typedef __attribute__((ext_vector_type(8))) _Float16 f16x8;

// ---------------------------------------------------------------------------
// Weight prepack: split weights into fp16 hi+lo (w ~= hi + lo, ~2^-22 rel
// residual) and arrange in MFMA B-fragment order.
// Layout: [tap][ch][g(4)][half(2)][lane(64)][r(8)] fp16,
//   oc = g*16 + (lane&15), cin = ch*32 + (lane>>4)*8 + r.
// ---------------------------------------------------------------------------
template <int CIN, int NCH>
__device__ inline void packone(short* p, const float* w, int e) {
  int r = e & 7;
  int l = (e >> 3) & 63;
  int half = (e >> 9) & 1;
  int g = (e >> 10) & 3;
  int tc = e >> 12;  // tap*NCH + ch
  int ch = tc & (NCH - 1);
  int tap = tc / NCH;
  int oc = g * 16 + (l & 15);
  int cin = ch * 32 + ((l >> 4) << 3) + r;
  float v = w[((size_t)oc * CIN + cin) * 9 + tap];
  _Float16 h = (_Float16)v;
  _Float16 lo = (_Float16)(v - (float)h);
  _Float16 sel = half ? lo : h;
  p[e] = __builtin_bit_cast(short, sel);
}

__global__ __launch_bounds__(256) void wpack_kernel(
    const float* __restrict__ w1, const float* __restrict__ w2,
    short* __restrict__ p1, short* __restrict__ p2) {
  int e = blockIdx.x * 256 + threadIdx.x;
  if (e < 73728) {
    packone<64, 2>(p1, w1, e);
  } else if (e < 73728 + 147456) {
    packone<128, 4>(p2, w2, e - 73728);
  }
}

// ---------------------------------------------------------------------------
// conv3x3 via MFMA implicit GEMM. fp32 accuracy via weight-only hi/lo fp16
// split (A rounded once to fp16: output err ~sqrt(K)*|ab|*2^-11 ~ 3e-4).
// Block: 4 waves, 8x32 px tile x 64 oc. K = 9 taps x NCH chunks of 32 cin.
// LDS: halo 10x34 px x 32 cin fp16 = 21760 B. Bank-quad XOR swizzle:
// slot' = g ^ ((px>>1)&3) -> any 8 consecutive px cover all 8 bank-quads
// (optimal for both ds_write_b128 staging and ds_read_b128 A-frags).
// B frags double-buffered in registers across taps (tap-pair ping-pong);
// tap-0 B prefetched under the staging phase.
// SPLIT: cin>=64 comes from inB (implicit channel concat).
// ---------------------------------------------------------------------------
template <int NCH, bool SPLIT, bool BNRELU>
__global__ __launch_bounds__(256, 1) void convmfma_kernel(
    const float* __restrict__ inA, const float* __restrict__ inB,
    const short* __restrict__ wpk, const float* __restrict__ bias,
    const float* __restrict__ bng, const float* __restrict__ bnb,
    const float* __restrict__ bnm, const float* __restrict__ bnv,
    float* __restrict__ out) {
  __shared__ __align__(16) short lds[10880];  // 21760 B
  char* ldsb = (char*)lds;
  const int t = threadIdx.x;
  const int lane = t & 63;
  const int wv = t >> 6;
  const int bx = blockIdx.x % 10, by = blockIdx.x / 10;
  const int x0 = bx * 32, y0 = by * 8;
  const int b = blockIdx.z;
  const int gsel = lane >> 4;

  f32x4 acc[4][4];
#pragma unroll
  for (int mi = 0; mi < 4; ++mi)
#pragma unroll
    for (int ni = 0; ni < 4; ++ni) acc[mi][ni] = (f32x4){0.f, 0.f, 0.f, 0.f};

  // halo-position base per mi (tile px -> halo px at tap center)
  int hbase[4];
#pragma unroll
  for (int mi = 0; mi < 4; ++mi) {
    int px = wv * 64 + mi * 16 + (lane & 15);
    hbase[mi] = ((px >> 5) + 1) * 34 + (px & 31) + 1;
  }

  f16x8 bhA[4], blA[4], bhB[4], blB[4];

  for (int ch = 0; ch < NCH; ++ch) {
    __syncthreads();  // protect LDS from prior chunk's readers

    // prefetch tap-0 B fragments (independent of LDS; lands during staging)
    {
      const short* wb = wpk + ((size_t)(0 * NCH + ch) << 12);
#pragma unroll
      for (int g = 0; g < 4; ++g) {
        bhA[g] = *(const f16x8*)(wb + g * 1024 + lane * 8);
        blA[g] = *(const f16x8*)(wb + g * 1024 + 512 + lane * 8);
      }
    }

    // ---- stage halo tile: 340 px x 32 cin, fp32 -> fp16 ----
#pragma unroll
    for (int it = 0; it < 6; ++it) {
      int task = it * 256 + t;  // < 1360 = 340 px * 4 cin-groups
      if (task < 1360) {
        int px = task % 340;
        int g8 = task / 340;
        int hr = px / 34, hc = px - hr * 34;
        int gy = y0 - 1 + hr, gx = x0 - 1 + hc;
        bool ok = (unsigned)gy < (unsigned)HH && (unsigned)gx < (unsigned)WW;
        int off = gy * WW + gx;
        f16x8 hv;
#pragma unroll
        for (int k = 0; k < 8; ++k) {
          int cin = ch * 32 + g8 * 8 + k;
          const float* src = (SPLIT && cin >= 64)
                                 ? inB + ((size_t)(b * 64 + cin - 64)) * HWP
                                 : inA + ((size_t)(b * 64 + cin)) * HWP;
          float v = ok ? src[off] : 0.f;
          hv[k] = (_Float16)v;
        }
        int slot = (g8 ^ ((px >> 1) & 3)) << 4;
        *(f16x8*)(ldsb + px * 64 + slot) = hv;
      }
    }
    __syncthreads();

    auto loadB = [&](f16x8* bh, f16x8* bl, int tap) {
      const short* wb = wpk + ((size_t)(tap * NCH + ch) << 12);
#pragma unroll
      for (int g = 0; g < 4; ++g) {
        bh[g] = *(const f16x8*)(wb + g * 1024 + lane * 8);
        bl[g] = *(const f16x8*)(wb + g * 1024 + 512 + lane * 8);
      }
    };
    auto compute = [&](const f16x8* bh, const f16x8* bl, int tap) {
      int dy = tap / 3 - 1, dx = tap - (tap / 3) * 3 - 1;
      int doff = dy * 34 + dx;
      f16x8 a[4];
#pragma unroll
      for (int mi = 0; mi < 4; ++mi) {
        int hp = hbase[mi] + doff;
        int addr = hp * 64 + (((gsel ^ ((hp >> 1) & 3))) << 4);
        a[mi] = *(const f16x8*)(ldsb + addr);
      }
#pragma unroll
      for (int mi = 0; mi < 4; ++mi)
#pragma unroll
        for (int ni = 0; ni < 4; ++ni) {
          acc[mi][ni] = __builtin_amdgcn_mfma_f32_16x16x32_f16(
              a[mi], bh[ni], acc[mi][ni], 0, 0, 0);
          acc[mi][ni] = __builtin_amdgcn_mfma_f32_16x16x32_f16(
              a[mi], bl[ni], acc[mi][ni], 0, 0, 0);
        }
    };

    // tap-pair ping-pong: B for tap+1 loads while tap computes
#pragma unroll 1
    for (int tp = 0; tp < 9; tp += 2) {
      if (tp + 1 < 9) loadB(bhB, blB, tp + 1);
      compute(bhA, blA, tp);
      if (tp + 1 < 9) {
        if (tp + 2 < 9) loadB(bhA, blA, tp + 2);
        compute(bhB, blB, tp + 1);
      }
    }
  }

  // ---- epilogue: C/D layout col=lane&15 (oc), row=(lane>>4)*4+reg (px) ----
#pragma unroll
  for (int ni = 0; ni < 4; ++ni) {
    int oc = ni * 16 + (lane & 15);
    float sc = 1.f, sh = 0.f;
    if constexpr (BNRELU) {
      sc = bng[oc] * rsqrtf(bnv[oc] + 1e-5f);
      sh = (bias[oc] - bnm[oc]) * sc + bnb[oc];
    }
#pragma unroll
    for (int mi = 0; mi < 4; ++mi) {
      int px = wv * 64 + mi * 16 + ((lane >> 4) << 2);
      int y = y0 + (px >> 5), x = x0 + (px & 31);
      f32x4 v = acc[mi][ni];
      if constexpr (BNRELU) {
#pragma unroll
        for (int r = 0; r < 4; ++r) v[r] = fmaxf(v[r] * sc + sh, 0.f);
      }
      *(f32x4*)&out[((size_t)(b * 64 + oc)) * HWP + y * WW + x] = v;
    }
  }
}

// ---------------------------------------------------------------------------
// pointwise (1x1) conv: 64 px x 64 oc per block, thread = 4 oc x 4 px.
// IO: weight global layout [in][out] (true) or [out][in] (false).
// EPI==0: plain store (D = kd @ ON).  EPI==1: PAM output epilogue:
//   out = coef * exp(q_h*k_w - M) * (acc + v_b) + x   (residual from LDS)
// ---------------------------------------------------------------------------
template <bool IO, int EPI>
__global__ __launch_bounds__(256) void pointwise_kernel(
    const float* __restrict__ xin, const float* __restrict__ wmat,
    const float* __restrict__ bias, const float* __restrict__ qpool,
    const float* __restrict__ kpool, const float* __restrict__ Mbuf,
    const float* __restrict__ coefb, float* __restrict__ out) {
  __shared__ float s_x[64][68];
  __shared__ float s_w[64][64];
  const int t = threadIdx.x;
  const int p0 = blockIdx.x * 64;
  const int b = blockIdx.y;
  for (int idx = t; idx < 4096; idx += 256) {
    int c = idx >> 6, p = idx & 63;
    s_x[c][p] = xin[((size_t)(b * 64 + c)) * HWP + p0 + p];
    s_w[c][p] = IO ? wmat[c * 64 + p] : wmat[p * 64 + c];
  }
  __syncthreads();
  const int og = t >> 4, pg = t & 15;
  float acc[4][4] = {};
  for (int c = 0; c < 64; ++c) {
    float4 xv = *(const float4*)&s_x[c][pg * 4];
    float4 wv = *(const float4*)&s_w[c][og * 4];
    const float* xp = &xv.x;
    const float* wp = &wv.x;
#pragma unroll
    for (int oi = 0; oi < 4; ++oi)
#pragma unroll
      for (int pi = 0; pi < 4; ++pi)
        acc[oi][pi] = fmaf(wp[oi], xp[pi], acc[oi][pi]);
  }
  const int h = p0 / WW;
  const int w0 = p0 - h * WW;
#pragma unroll
  for (int oi = 0; oi < 4; ++oi) {
    int oc = og * 4 + oi;
    float4 r;
    float* rp = &r.x;
    if constexpr (EPI == 0) {
#pragma unroll
      for (int pi = 0; pi < 4; ++pi) rp[pi] = acc[oi][pi];
    } else {
      int bc = b * 64 + oc;
      float qh = qpool[bc * HH + h];
      float Mv = Mbuf[bc];
      float cf = coefb[bc];
      float vb = bias[oc];
#pragma unroll
      for (int pi = 0; pi < 4; ++pi) {
        int wc = w0 + pg * 4 + pi;
        float kw = kpool[bc * WW + wc];
        float vv = acc[oi][pi] + vb;
        rp[pi] = cf * __expf(qh * kw - Mv) * vv + s_x[oc][pg * 4 + pi];
      }
    }
    *(float4*)&out[((size_t)(b * 64 + oc)) * HWP + p0 + pg * 4] = r;
  }
}

// ---------------------------------------------------------------------------
// gate: conv s2/p1 (1->9 ch) + BN + ReLU + per-block partial GAP sums.
// 16 blocks per batch, grid-stride; NO atomics. prep_kernel folds partials.
// ---------------------------------------------------------------------------
__global__ __launch_bounds__(256) void gate_kernel(
    const float* __restrict__ illu, const float* __restrict__ tw,
    const float* __restrict__ tb, const float* __restrict__ tg,
    const float* __restrict__ tbeta, const float* __restrict__ tm,
    const float* __restrict__ tv, float* __restrict__ gate_part) {
  const int b = blockIdx.x >> 4;        // 4 batches x 16 blocks
  const int blk = blockIdx.x & 15;
  const float* ip = illu + (size_t)b * (2 * HH) * (2 * WW);
  float sums[9] = {0.f, 0.f, 0.f, 0.f, 0.f, 0.f, 0.f, 0.f, 0.f};
  float sc9[9], sh9[9];
#pragma unroll
  for (int n = 0; n < 9; ++n) {
    sc9[n] = tg[n] * rsqrtf(tv[n] + 1e-5f);
    sh9[n] = (tb[n] - tm[n]) * sc9[n] + tbeta[n];
  }
  for (int p = blk * 256 + threadIdx.x; p < HWP; p += 4096) {
    const int oh = p / WW, ow = p - (p / WW) * WW;
    float v[9];
#pragma unroll
    for (int ky = 0; ky < 3; ++ky)
#pragma unroll
      for (int kx = 0; kx < 3; ++kx) {
        int iy = 2 * oh - 1 + ky;
        int ix = 2 * ow - 1 + kx;
        v[ky * 3 + kx] = ((unsigned)iy < 2 * HH && (unsigned)ix < 2 * WW)
                             ? ip[iy * (2 * WW) + ix] : 0.f;
      }
#pragma unroll
    for (int n = 0; n < 9; ++n) {
      float cv = 0.f;
#pragma unroll
      for (int k = 0; k < 9; ++k) cv = fmaf(tw[n * 9 + k], v[k], cv);
      sums[n] += fmaxf(cv * sc9[n] + sh9[n], 0.f);
    }
  }
#pragma unroll
  for (int n = 0; n < 9; ++n)
    for (int off = 32; off; off >>= 1) sums[n] += __shfl_down(sums[n], off);
  __shared__ float part[4][9];
  const int wid = threadIdx.x >> 6, lane = threadIdx.x & 63;
  if (lane == 0) {
#pragma unroll
    for (int n = 0; n < 9; ++n) part[wid][n] = sums[n];
  }
  __syncthreads();
  if (threadIdx.x < 9) {
    int n = threadIdx.x;
    gate_part[blockIdx.x * 9 + n] =
        part[0][n] + part[1][n] + part[2][n] + part[3][n];
  }
}

// ---------------------------------------------------------------------------
// prep: block 0 -> fold gate partials + normalize s[b][9];
//       blocks 1..16 -> kd[c][o] = sum3x3 conv_w
// ---------------------------------------------------------------------------
__global__ void prep_kernel(const float* __restrict__ gate_part,
                            const float* __restrict__ conv_w,
                            float* __restrict__ s_out,
                            float* __restrict__ kd) {
  if (blockIdx.x == 0) {
    int t = threadIdx.x;
    if (t < 4) {
      float g[9];
      float S = 0.f;
      for (int n = 0; n < 9; ++n) {
        float acc = 0.f;
        for (int k = 0; k < 16; ++k) acc += gate_part[(t * 16 + k) * 9 + n];
        g[n] = acc * (1.f / (float)HWP);
        S += fabsf(g[n]);
      }
      float inv = 1.f / (S + 1e-8f);
      for (int n = 0; n < 9; ++n) s_out[t * 9 + n] = g[n] * inv;
    }
  } else {
    int gid = (blockIdx.x - 1) * 256 + threadIdx.x;  // < 4096
    int c = gid >> 6, o = gid & 63;
    const float* wp = conv_w + ((size_t)o * 64 + c) * 9;
    float sum = 0.f;
#pragma unroll
    for (int k = 0; k < 9; ++k) sum += wp[k];
    kd[c * 64 + o] = sum;  // [in][out] layout
  }
}

// ---------------------------------------------------------------------------
// shift: NN = ON - theta * sum_n s[b][n] * D[b,c, refl(i+dy), refl(j+dx)]
// ---------------------------------------------------------------------------
__global__ __launch_bounds__(256) void shift_kernel(
    const float* __restrict__ ON, const float* __restrict__ D,
    const float* __restrict__ s, const float* __restrict__ theta,
    float* __restrict__ NN) {
  const int b = blockIdx.z, c = blockIdx.y;
  const int p = blockIdx.x * 256 + threadIdx.x;
  const int i = p / WW, j = p - (p / WW) * WW;
  const float* Dp = D + ((size_t)(b * 64 + c)) * HWP;
  const float th = theta[0];
  float acc = 0.f;
#pragma unroll
  for (int dy = -1; dy <= 1; ++dy)
#pragma unroll
    for (int dx = -1; dx <= 1; ++dx) {
      int ri = i + dy;
      ri = ri < 0 ? 1 : (ri >= HH ? HH - 2 : ri);
      int rj = j + dx;
      rj = rj < 0 ? 1 : (rj >= WW ? WW - 2 : rj);
      acc = fmaf(s[b * 9 + (dy + 1) * 3 + (dx + 1)], Dp[ri * WW + rj], acc);
    }
  size_t idx = ((size_t)(b * 64 + c)) * HWP + p;
  NN[idx] = ON[idx] - th * acc;
}

// ---------------------------------------------------------------------------
// row / col means of x
// ---------------------------------------------------------------------------
__global__ __launch_bounds__(256) void rowmean_kernel(const float* __restrict__ x,
                                                      float* __restrict__ xrow) {
  int row = blockIdx.x * 4 + (threadIdx.x >> 6);
  int lane = threadIdx.x & 63;
  const float* p = x + (size_t)row * WW;
  float s = p[lane] + p[lane + 64] + p[lane + 128] + p[lane + 192] + p[lane + 256];
  for (int off = 32; off; off >>= 1) s += __shfl_down(s, off);
  if (lane == 0) xrow[row] = s * (1.f / (float)WW);
}

__global__ void colmean_kernel(const float* __restrict__ x,
                               float* __restrict__ xcol) {
  int bc = blockIdx.x;
  int w = threadIdx.x;
  const float* p = x + (size_t)bc * HWP;
  float s = 0.f;
  for (int h = 0; h < HH; ++h) s += p[h * WW + w];
  xcol[bc * WW + w] = s * (1.f / (float)HH);
}

// ---------------------------------------------------------------------------
// pool: qpool = q_w @ xrow + q_b ; kpool = k_w @ xcol + k_b
// ---------------------------------------------------------------------------
__global__ __launch_bounds__(256) void pool_kernel(
    const float* __restrict__ xrow, const float* __restrict__ xcol,
    const float* __restrict__ qw, const float* __restrict__ qb,
    const float* __restrict__ kw, const float* __restrict__ kb,
    float* __restrict__ qpool, float* __restrict__ kpool) {
  int gid = blockIdx.x * 256 + threadIdx.x;
  if (gid < 4 * 64 * HH) {
    int b = gid / (64 * HH);
    int c = (gid / HH) & 63;
    int h = gid - (gid / HH) * HH;
    float s = qb[c];
    const float* xr = xrow + (size_t)(b * 64) * HH + h;
    for (int c2 = 0; c2 < 64; ++c2) s = fmaf(qw[c * 64 + c2], xr[c2 * HH], s);
    qpool[gid] = s;
  } else {
    int g2 = gid - 4 * 64 * HH;
    int b = g2 / (64 * WW);
    int c = (g2 / WW) & 63;
    int w = g2 - (g2 / WW) * WW;
    float s = kb[c];
    const float* xc = xcol + (size_t)(b * 64) * WW + w;
    for (int c2 = 0; c2 < 64; ++c2) s = fmaf(kw[c * 64 + c2], xc[c2 * WW], s);
    kpool[g2] = s;
  }
}

// ---------------------------------------------------------------------------
// mz: per (b,c): exact max of rank-1 energy from extremes; Z = sum exp(e-M);
// coef = pam_gamma / Z
// ---------------------------------------------------------------------------
__global__ __launch_bounds__(256) void mz_kernel(
    const float* __restrict__ qpool, const float* __restrict__ kpool,
    const float* __restrict__ pam_gamma, float* __restrict__ Mbuf,
    float* __restrict__ coefb) {
  int bc = blockIdx.x;
  __shared__ float qs[HH];
  __shared__ float ks[WW];
  __shared__ float red[4][4];
  __shared__ float zred[4];
  __shared__ float sM;
  int t = threadIdx.x;
  for (int i = t; i < HH; i += 256) qs[i] = qpool[bc * HH + i];
  for (int i = t; i < WW; i += 256) ks[i] = kpool[bc * WW + i];
  __syncthreads();
  float mq = -1e30f, nq = 1e30f, mk = -1e30f, nk = 1e30f;
  for (int i = t; i < HH; i += 256) {
    float v = qs[i]; mq = fmaxf(mq, v); nq = fminf(nq, v);
  }
  for (int i = t; i < WW; i += 256) {
    float v = ks[i]; mk = fmaxf(mk, v); nk = fminf(nk, v);
  }
  for (int off = 32; off; off >>= 1) {
    mq = fmaxf(mq, __shfl_down(mq, off));
    nq = fminf(nq, __shfl_down(nq, off));
    mk = fmaxf(mk, __shfl_down(mk, off));
    nk = fminf(nk, __shfl_down(nk, off));
  }
  int wid = t >> 6, lane = t & 63;
  if (lane == 0) { red[wid][0] = mq; red[wid][1] = nq; red[wid][2] = mk; red[wid][3] = nk; }
  __syncthreads();
  if (t == 0) {
    mq = red[0][0]; nq = red[0][1]; mk = red[0][2]; nk = red[0][3];
    for (int wv = 1; wv < 4; ++wv) {
      mq = fmaxf(mq, red[wv][0]); nq = fminf(nq, red[wv][1]);
      mk = fmaxf(mk, red[wv][2]); nk = fminf(nk, red[wv][3]);
    }
    sM = fmaxf(fmaxf(mq * mk, mq * nk), fmaxf(nq * mk, nq * nk));
  }
  __syncthreads();
  float M = sM;
  float z = 0.f;
  for (int h = 0; h < HH; ++h) {
    float qv = qs[h];
    for (int w = t; w < WW; w += 256) z += __expf(qv * ks[w] - M);
  }
  for (int off = 32; off; off >>= 1) z += __shfl_down(z, off);
  if (lane == 0) zred[wid] = z;
  __syncthreads();
  if (t == 0) {
    float Z = zred[0] + zred[1] + zred[2] + zred[3];
    Mbuf[bc] = M;
    coefb[bc] = pam_gamma[0] / Z;
  }
}

// ---------------------------------------------------------------------------
extern "C" void kernel_launch(void* const* d_in, const int* in_sizes, int n_in,
                              void* d_out, int out_size, void* d_ws,
                              size_t ws_size, hipStream_t stream) {
  const float* lidar    = (const float*)d_in[0];
  const float* guidance = (const float*)d_in[1];
  const float* illu     = (const float*)d_in[2];
  const float* conv_w   = (const float*)d_in[3];
  const float* tw       = (const float*)d_in[4];
  const float* tb       = (const float*)d_in[5];
  const float* tg       = (const float*)d_in[6];
  const float* tbeta    = (const float*)d_in[7];
  const float* tm       = (const float*)d_in[8];
  const float* tv       = (const float*)d_in[9];
  const float* rgbd_w   = (const float*)d_in[10];
  const float* rgbd_b   = (const float*)d_in[11];
  const float* bnr_g    = (const float*)d_in[12];
  const float* bnr_b    = (const float*)d_in[13];
  const float* bnr_m    = (const float*)d_in[14];
  const float* bnr_v    = (const float*)d_in[15];
  const float* q_w      = (const float*)d_in[16];
  const float* q_b      = (const float*)d_in[17];
  const float* k_w      = (const float*)d_in[18];
  const float* k_b      = (const float*)d_in[19];
  const float* v_w      = (const float*)d_in[20];
  const float* v_b      = (const float*)d_in[21];
  const float* pgm      = (const float*)d_in[22];
  const float* theta    = (const float*)d_in[23];

  const size_t PLANE = (size_t)4 * 64 * HWP;  // 13,107,200 floats
  float* ws = (float*)d_ws;
  float* bufA = ws;               // ON, later x
  float* bufD = ws + PLANE;       // D
  float* bufN = ws + 2 * PLANE;   // new_normal
  float* gate_part = ws + 3 * PLANE;       // 64*9 = 576 (pad to 640)
  float* s_buf = gate_part + 640;          // 36 (pad to 64)
  float* kd    = s_buf + 64;               // 4096
  float* xrow  = kd + 4096;                // 40960
  float* xcol  = xrow + 40960;             // 81920
  float* qpool = xcol + 81920;             // 40960
  float* kpool = qpool + 40960;            // 81920
  float* Mbuf  = kpool + 81920;            // 256
  float* coefb = Mbuf + 256;               // 256
  short* wpk1  = (short*)(coefb + 256);    // 73728 shorts
  short* wpk2  = wpk1 + 73728;             // 147456 shorts

  wpack_kernel<<<864, 256, 0, stream>>>(conv_w, rgbd_w, wpk1, wpk2);

  gate_kernel<<<64, 256, 0, stream>>>(illu, tw, tb, tg, tbeta, tm, tv,
                                      gate_part);
  prep_kernel<<<17, 256, 0, stream>>>(gate_part, conv_w, s_buf, kd);

  // ON = conv3x3(guidance, conv_w)  (no bias)
  convmfma_kernel<2, false, false><<<dim3(200, 1, 4), 256, 0, stream>>>(
      guidance, nullptr, wpk1, nullptr, nullptr, nullptr, nullptr, nullptr,
      bufA);

  // D = kd @ ON (1x1)
  pointwise_kernel<true, 0><<<dim3(800, 4), 256, 0, stream>>>(
      bufA, kd, nullptr, nullptr, nullptr, nullptr, nullptr, bufD);

  // NN = ON - theta * sum_n s_n * shift_n(D)
  shift_kernel<<<dim3(200, 64, 4), 256, 0, stream>>>(bufA, bufD, s_buf, theta,
                                                     bufN);

  // x = relu(bn(conv3x3(cat(NN, lidar), rgbd_w) + rgbd_b))  -> overwrite bufA
  convmfma_kernel<4, true, true><<<dim3(200, 1, 4), 256, 0, stream>>>(
      bufN, lidar, wpk2, rgbd_b, bnr_g, bnr_b, bnr_m, bnr_v, bufA);

  rowmean_kernel<<<10240, 256, 0, stream>>>(bufA, xrow);
  colmean_kernel<<<256, 320, 0, stream>>>(bufA, xcol);
  pool_kernel<<<480, 256, 0, stream>>>(xrow, xcol, q_w, q_b, k_w, k_b, qpool,
                                       kpool);
  mz_kernel<<<256, 256, 0, stream>>>(qpool, kpool, pgm, Mbuf, coefb);

  // out = coef*exp(qh*kw - M)*(v_w@x + v_b) + x
  pointwise_kernel<false, 1><<<dim3(800, 4), 256, 0, stream>>>(
      bufA, v_w, v_b, qpool, kpool, Mbuf, coefb, (float*)d_out);
}

// Round 6
// 479.606 us; speedup vs baseline: 1.3252x; 1.3252x over previous
//
#include <hip/hip_runtime.h>
#include <math.h>

// Problem constants (B=4, C=64, H=160, W=320)
#define HH 160
#define WW 320
#define HWP (HH * WW)   // 51200

typedef __attribute__((ext_vector_type(4))) float f32x4;
typedef __attribute__((ext_vector_type(8))) _Float16 f16x8;
typedef __attribute__((ext_vector_type(4))) unsigned int u32x4;
typedef __attribute__((ext_vector_type(2))) unsigned int u32x2;

__device__ __forceinline__ unsigned short f2h(float x) {
  _Float16 h = (_Float16)x;
  return __builtin_bit_cast(unsigned short, h);
}
__device__ __forceinline__ float h2f(unsigned short u) {
  return (float)__builtin_bit_cast(_Float16, u);
}

// global -> LDS direct DMA, 16B per lane. LDS dest is wave-uniform base +
// lane*16 (m104); global source is per-lane (pre-swizzled).
__device__ __forceinline__ void gload16(const void* g, void* l) {
  __builtin_amdgcn_global_load_lds(
      (const __attribute__((address_space(1))) void*)g,
      (__attribute__((address_space(3))) void*)l, 16, 0, 0);
}

// ---------------------------------------------------------------------------
// Weight prepack: split weights into fp16 hi+lo (w ~= hi+lo) in MFMA
// B-fragment order: [tap][ch][g(4)][half(2)][lane(64)][r(8)] fp16,
//   oc = g*16 + (lane&15), cin = ch*32 + (lane>>4)*8 + r.
// ---------------------------------------------------------------------------
template <int CIN, int NCH>
__device__ inline void packone(short* p, const float* w, int e) {
  int r = e & 7;
  int l = (e >> 3) & 63;
  int half = (e >> 9) & 1;
  int g = (e >> 10) & 3;
  int tc = e >> 12;  // tap*NCH + ch
  int ch = tc & (NCH - 1);
  int tap = tc / NCH;
  int oc = g * 16 + (l & 15);
  int cin = ch * 32 + ((l >> 4) << 3) + r;
  float v = w[((size_t)oc * CIN + cin) * 9 + tap];
  _Float16 h = (_Float16)v;
  _Float16 lo = (_Float16)(v - (float)h);
  _Float16 sel = half ? lo : h;
  p[e] = __builtin_bit_cast(short, sel);
}

__global__ __launch_bounds__(256) void wpack_kernel(
    const float* __restrict__ w1, const float* __restrict__ w2,
    short* __restrict__ p1, short* __restrict__ p2) {
  int e = blockIdx.x * 256 + threadIdx.x;
  if (e < 73728) {
    packone<64, 2>(p1, w1, e);
  } else if (e < 73728 + 147456) {
    packone<128, 4>(p2, w2, e - 73728);
  }
}

// ---------------------------------------------------------------------------
// Planar fp32 -> NHWC-chunked f16: dst[(b*NCHD + ch0 + ch)*HWP + px][cin32].
// One thread per pixel; 64 strided (coalesced-across-lanes) loads; 64B stores.
// ---------------------------------------------------------------------------
__global__ __launch_bounds__(256) void cvt_kernel(
    const float* __restrict__ src, unsigned short* __restrict__ dst,
    int nchd, int ch0) {
  int px = blockIdx.x * 256 + threadIdx.x;
  int b = blockIdx.y;
  const float* sp = src + (size_t)(b * 64) * HWP + px;
#pragma unroll
  for (int ch = 0; ch < 2; ++ch) {
    unsigned pk[16];
#pragma unroll
    for (int j = 0; j < 16; ++j) {
      float v0 = sp[(size_t)(ch * 32 + j * 2) * HWP];
      float v1 = sp[(size_t)(ch * 32 + j * 2 + 1) * HWP];
      pk[j] = (unsigned)f2h(v0) | ((unsigned)f2h(v1) << 16);
    }
    u32x4* dq = (u32x4*)(dst + ((size_t)(b * nchd + ch0 + ch) * HWP + px) * 32);
#pragma unroll
    for (int q = 0; q < 4; ++q)
      dq[q] = (u32x4){pk[q * 4], pk[q * 4 + 1], pk[q * 4 + 2], pk[q * 4 + 3]};
  }
}

// ---------------------------------------------------------------------------
// conv3x3 via MFMA implicit GEMM on pre-converted NHWC f16 input.
// Block: 4 waves, 8x32 px x 64 oc. K = 9 taps x NCH chunks of 32 cin.
// Staging: global_load_lds DMA (16B/lane), linear LDS dest, inverse-swizzled
// source; granule XOR swizzle (slot = g ^ ((px>>1)&3)) -> 2-way-free ds_read.
// Double-buffered LDS across chunks: issue chunk c+1 DMA, compute chunk c,
// barrier (drains DMA that had the whole compute phase to land).
// B (weight) fragments hi/lo f16, register ping-pong across taps.
// ---------------------------------------------------------------------------
template <int NCH, bool BNRELU>
__global__ __launch_bounds__(256, 1) void convmfma_kernel(
    const unsigned short* __restrict__ in16, const short* __restrict__ wpk,
    const char* __restrict__ zeropad, const float* __restrict__ bias,
    const float* __restrict__ bng, const float* __restrict__ bnb,
    const float* __restrict__ bnm, const float* __restrict__ bnv,
    float* __restrict__ out) {
  __shared__ __align__(16) char lds[2][24576];  // 340(+pad) px * 64B, x2
  const int t = threadIdx.x;
  const int lane = t & 63;
  const int wv = t >> 6;
  const int bx = blockIdx.x % 10, by = blockIdx.x / 10;
  const int x0 = bx * 32, y0 = by * 8;
  const int b = blockIdx.z;
  const int g = lane >> 4;

  f32x4 acc[4][4];
#pragma unroll
  for (int mi = 0; mi < 4; ++mi)
#pragma unroll
    for (int ni = 0; ni < 4; ++ni) acc[mi][ni] = (f32x4){0.f, 0.f, 0.f, 0.f};

  int hbase[4];
#pragma unroll
  for (int mi = 0; mi < 4; ++mi) {
    int px = wv * 64 + mi * 16 + (lane & 15);
    hbase[mi] = ((px >> 5) + 1) * 34 + (px & 31) + 1;
  }

  auto stage = [&](int ch, char* buf) {
    const char* cb = (const char*)in16 + ((size_t)(b * NCH + ch) * HWP) * 64;
#pragma unroll
    for (int it = 0; it < 6; ++it) {
      int tb = it * 256 + wv * 64;  // wave-uniform LDS base (granules)
      int tau = tb + lane;
      int px = tau >> 2, sl = tau & 3;
      int hr = px / 34, hc = px - hr * 34;
      int gy = y0 - 1 + hr, gx = x0 - 1 + hc;
      bool ok = (px < 340) && ((unsigned)gy < (unsigned)HH) &&
                ((unsigned)gx < (unsigned)WW);
      int gs = sl ^ ((px >> 1) & 3);  // inverse swizzle on SOURCE
      const char* src =
          ok ? cb + ((size_t)(gy * WW + gx)) * 64 + gs * 16 : zeropad + lane * 16;
      gload16(src, buf + tb * 16);
    }
  };
  auto loadB = [&](f16x8* bh, f16x8* bl, int tap, int ch) {
    const short* wb = wpk + ((size_t)(tap * NCH + ch) << 12);
#pragma unroll
    for (int gg = 0; gg < 4; ++gg) {
      bh[gg] = *(const f16x8*)(wb + gg * 1024 + lane * 8);
      bl[gg] = *(const f16x8*)(wb + gg * 1024 + 512 + lane * 8);
    }
  };
  auto compute = [&](const char* buf, const f16x8* bh, const f16x8* bl,
                     int tap) {
    int dy = tap / 3 - 1, dx = tap - (tap / 3) * 3 - 1;
    int doff = dy * 34 + dx;
    f16x8 a[4];
#pragma unroll
    for (int mi = 0; mi < 4; ++mi) {
      int hp = hbase[mi] + doff;
      a[mi] = *(const f16x8*)(buf + hp * 64 + ((g ^ ((hp >> 1) & 3)) << 4));
    }
#pragma unroll
    for (int mi = 0; mi < 4; ++mi)
#pragma unroll
      for (int ni = 0; ni < 4; ++ni) {
        acc[mi][ni] = __builtin_amdgcn_mfma_f32_16x16x32_f16(
            a[mi], bh[ni], acc[mi][ni], 0, 0, 0);
        acc[mi][ni] = __builtin_amdgcn_mfma_f32_16x16x32_f16(
            a[mi], bl[ni], acc[mi][ni], 0, 0, 0);
      }
  };

  f16x8 bhA[4], blA[4], bhB[4], blB[4];
  stage(0, lds[0]);
  loadB(bhA, blA, 0, 0);
  __syncthreads();  // drain prologue DMA
  int cur = 0;
#pragma unroll 1
  for (int ch = 0; ch < NCH; ++ch) {
    if (ch + 1 < NCH) stage(ch + 1, lds[cur ^ 1]);  // fire-and-forget
#pragma unroll 1
    for (int tp = 0; tp < 9; tp += 2) {
      if (tp + 1 < 9) loadB(bhB, blB, tp + 1, ch);
      compute(lds[cur], bhA, blA, tp);
      if (tp + 1 < 9) {
        if (tp + 2 < 9) loadB(bhA, blA, tp + 2, ch);
        compute(lds[cur], bhB, blB, tp + 1);
      }
    }
    if (ch + 1 < NCH) loadB(bhA, blA, 0, ch + 1);
    __syncthreads();  // drains next-chunk DMA (covered by compute above)
    cur ^= 1;
  }

  // epilogue: C/D layout col=lane&15 (oc), row=(lane>>4)*4+reg (px)
#pragma unroll
  for (int ni = 0; ni < 4; ++ni) {
    int oc = ni * 16 + (lane & 15);
    float sc = 1.f, sh = 0.f;
    if constexpr (BNRELU) {
      sc = bng[oc] * rsqrtf(bnv[oc] + 1e-5f);
      sh = (bias[oc] - bnm[oc]) * sc + bnb[oc];
    }
#pragma unroll
    for (int mi = 0; mi < 4; ++mi) {
      int px = wv * 64 + mi * 16 + ((lane >> 4) << 2);
      int y = y0 + (px >> 5), x = x0 + (px & 31);
      f32x4 v = acc[mi][ni];
      if constexpr (BNRELU) {
#pragma unroll
        for (int r = 0; r < 4; ++r) v[r] = fmaxf(v[r] * sc + sh, 0.f);
      }
      *(f32x4*)&out[((size_t)(b * 64 + oc)) * HWP + y * WW + x] = v;
    }
  }
}

// ---------------------------------------------------------------------------
// pointwise (1x1) conv: 64 px x 64 oc per block, thread = 4 oc x 4 px.
// IO: weight layout [in][out] (true) / [out][in] (false).
// EPI==0: plain store (H16: f16 planar out for D).  EPI==1: PAM epilogue.
// ---------------------------------------------------------------------------
template <bool IO, int EPI, bool H16>
__global__ __launch_bounds__(256) void pointwise_kernel(
    const float* __restrict__ xin, const float* __restrict__ wmat,
    const float* __restrict__ bias, const float* __restrict__ qpool,
    const float* __restrict__ kpool, const float* __restrict__ Mbuf,
    const float* __restrict__ coefb, void* __restrict__ outv) {
  __shared__ float s_x[64][68];
  __shared__ float s_w[64][64];
  const int t = threadIdx.x;
  const int p0 = blockIdx.x * 64;
  const int b = blockIdx.y;
  for (int idx = t; idx < 4096; idx += 256) {
    int c = idx >> 6, p = idx & 63;
    s_x[c][p] = xin[((size_t)(b * 64 + c)) * HWP + p0 + p];
    s_w[c][p] = IO ? wmat[c * 64 + p] : wmat[p * 64 + c];
  }
  __syncthreads();
  const int og = t >> 4, pg = t & 15;
  float acc[4][4] = {};
  for (int c = 0; c < 64; ++c) {
    float4 xv = *(const float4*)&s_x[c][pg * 4];
    float4 wv = *(const float4*)&s_w[c][og * 4];
    const float* xp = &xv.x;
    const float* wp = &wv.x;
#pragma unroll
    for (int oi = 0; oi < 4; ++oi)
#pragma unroll
      for (int pi = 0; pi < 4; ++pi)
        acc[oi][pi] = fmaf(wp[oi], xp[pi], acc[oi][pi]);
  }
  const int h = p0 / WW;
  const int w0 = p0 - h * WW;
#pragma unroll
  for (int oi = 0; oi < 4; ++oi) {
    int oc = og * 4 + oi;
    if constexpr (EPI == 0 && H16) {
      unsigned short* oh = (unsigned short*)outv;
      unsigned lo = (unsigned)f2h(acc[oi][0]) | ((unsigned)f2h(acc[oi][1]) << 16);
      unsigned hi = (unsigned)f2h(acc[oi][2]) | ((unsigned)f2h(acc[oi][3]) << 16);
      *(u32x2*)&oh[((size_t)(b * 64 + oc)) * HWP + p0 + pg * 4] = (u32x2){lo, hi};
    } else {
      float* out = (float*)outv;
      float4 r;
      float* rp = &r.x;
      if constexpr (EPI == 0) {
#pragma unroll
        for (int pi = 0; pi < 4; ++pi) rp[pi] = acc[oi][pi];
      } else {
        int bc = b * 64 + oc;
        float qh = qpool[bc * HH + h];
        float Mv = Mbuf[bc];
        float cf = coefb[bc];
        float vb = bias[oc];
#pragma unroll
        for (int pi = 0; pi < 4; ++pi) {
          int wc = w0 + pg * 4 + pi;
          float kw = kpool[bc * WW + wc];
          float vv = acc[oi][pi] + vb;
          rp[pi] = cf * __expf(qh * kw - Mv) * vv + s_x[oc][pg * 4 + pi];
        }
      }
      *(float4*)&out[((size_t)(b * 64 + oc)) * HWP + p0 + pg * 4] = r;
    }
  }
}

// ---------------------------------------------------------------------------
// gate: conv s2/p1 (1->9) + BN + ReLU + per-block partial GAP sums (no atomics)
// ---------------------------------------------------------------------------
__global__ __launch_bounds__(256) void gate_kernel(
    const float* __restrict__ illu, const float* __restrict__ tw,
    const float* __restrict__ tb, const float* __restrict__ tg,
    const float* __restrict__ tbeta, const float* __restrict__ tm,
    const float* __restrict__ tv, float* __restrict__ gate_part) {
  const int b = blockIdx.x >> 4;
  const int blk = blockIdx.x & 15;
  const float* ip = illu + (size_t)b * (2 * HH) * (2 * WW);
  float sums[9] = {0.f, 0.f, 0.f, 0.f, 0.f, 0.f, 0.f, 0.f, 0.f};
  float sc9[9], sh9[9];
#pragma unroll
  for (int n = 0; n < 9; ++n) {
    sc9[n] = tg[n] * rsqrtf(tv[n] + 1e-5f);
    sh9[n] = (tb[n] - tm[n]) * sc9[n] + tbeta[n];
  }
  for (int p = blk * 256 + threadIdx.x; p < HWP; p += 4096) {
    const int oh = p / WW, ow = p - (p / WW) * WW;
    float v[9];
#pragma unroll
    for (int ky = 0; ky < 3; ++ky)
#pragma unroll
      for (int kx = 0; kx < 3; ++kx) {
        int iy = 2 * oh - 1 + ky;
        int ix = 2 * ow - 1 + kx;
        v[ky * 3 + kx] = ((unsigned)iy < 2 * HH && (unsigned)ix < 2 * WW)
                             ? ip[iy * (2 * WW) + ix] : 0.f;
      }
#pragma unroll
    for (int n = 0; n < 9; ++n) {
      float cv = 0.f;
#pragma unroll
      for (int k = 0; k < 9; ++k) cv = fmaf(tw[n * 9 + k], v[k], cv);
      sums[n] += fmaxf(cv * sc9[n] + sh9[n], 0.f);
    }
  }
#pragma unroll
  for (int n = 0; n < 9; ++n)
    for (int off = 32; off; off >>= 1) sums[n] += __shfl_down(sums[n], off);
  __shared__ float part[4][9];
  const int wid = threadIdx.x >> 6, lane = threadIdx.x & 63;
  if (lane == 0) {
#pragma unroll
    for (int n = 0; n < 9; ++n) part[wid][n] = sums[n];
  }
  __syncthreads();
  if (threadIdx.x < 9) {
    int n = threadIdx.x;
    gate_part[blockIdx.x * 9 + n] =
        part[0][n] + part[1][n] + part[2][n] + part[3][n];
  }
}

// ---------------------------------------------------------------------------
// prep: block 0 -> fold partials + normalize s[b][9]; blocks 1..16 -> kd
// ---------------------------------------------------------------------------
__global__ void prep_kernel(const float* __restrict__ gate_part,
                            const float* __restrict__ conv_w,
                            float* __restrict__ s_out,
                            float* __restrict__ kd) {
  if (blockIdx.x == 0) {
    int t = threadIdx.x;
    if (t < 4) {
      float g[9];
      float S = 0.f;
      for (int n = 0; n < 9; ++n) {
        float acc = 0.f;
        for (int k = 0; k < 16; ++k) acc += gate_part[(t * 16 + k) * 9 + n];
        g[n] = acc * (1.f / (float)HWP);
        S += fabsf(g[n]);
      }
      float inv = 1.f / (S + 1e-8f);
      for (int n = 0; n < 9; ++n) s_out[t * 9 + n] = g[n] * inv;
    }
  } else {
    int gid = (blockIdx.x - 1) * 256 + threadIdx.x;  // < 4096
    int c = gid >> 6, o = gid & 63;
    const float* wp = conv_w + ((size_t)o * 64 + c) * 9;
    float sum = 0.f;
#pragma unroll
    for (int k = 0; k < 9; ++k) sum += wp[k];
    kd[c * 64 + o] = sum;  // [in][out]
  }
}

// ---------------------------------------------------------------------------
// shift + convert: NN = ON - theta * sum_n s_n * shift_n(D) written DIRECTLY
// as f16 NHWC chunks 0,1 of cat16 (the conv2 staging layout).
// ---------------------------------------------------------------------------
__global__ __launch_bounds__(256) void shift_cvt_kernel(
    const float* __restrict__ ON, const unsigned short* __restrict__ D16,
    const float* __restrict__ s, const float* __restrict__ theta,
    unsigned short* __restrict__ cat16) {
  const int px = blockIdx.x * 256 + threadIdx.x;
  const int b = blockIdx.y;
  const int i = px / WW, j = px - (px / WW) * WW;
  int off[9];
#pragma unroll
  for (int dy = -1; dy <= 1; ++dy)
#pragma unroll
    for (int dx = -1; dx <= 1; ++dx) {
      int ri = i + dy;
      ri = ri < 0 ? 1 : (ri >= HH ? HH - 2 : ri);
      int rj = j + dx;
      rj = rj < 0 ? 1 : (rj >= WW ? WW - 2 : rj);
      off[(dy + 1) * 3 + (dx + 1)] = ri * WW + rj;
    }
  float sw[9];
#pragma unroll
  for (int n = 0; n < 9; ++n) sw[n] = s[b * 9 + n];
  const float th = theta[0];
#pragma unroll
  for (int ch = 0; ch < 2; ++ch) {
    unsigned pk[16];
#pragma unroll
    for (int q = 0; q < 16; ++q) {
      unsigned short hh[2];
#pragma unroll
      for (int e = 0; e < 2; ++e) {
        int c = ch * 32 + q * 2 + e;
        const unsigned short* Dp = D16 + (size_t)(b * 64 + c) * HWP;
        float a = 0.f;
#pragma unroll
        for (int n = 0; n < 9; ++n) a = fmaf(sw[n], h2f(Dp[off[n]]), a);
        float nn = ON[(size_t)(b * 64 + c) * HWP + px] - th * a;
        hh[e] = f2h(nn);
      }
      pk[q] = (unsigned)hh[0] | ((unsigned)hh[1] << 16);
    }
    u32x4* dq = (u32x4*)(cat16 + ((size_t)(b * 4 + ch) * HWP + px) * 32);
#pragma unroll
    for (int q = 0; q < 4; ++q)
      dq[q] = (u32x4){pk[q * 4], pk[q * 4 + 1], pk[q * 4 + 2], pk[q * 4 + 3]};
  }
}

// ---------------------------------------------------------------------------
// row / col means of x
// ---------------------------------------------------------------------------
__global__ __launch_bounds__(256) void rowmean_kernel(const float* __restrict__ x,
                                                      float* __restrict__ xrow) {
  int row = blockIdx.x * 4 + (threadIdx.x >> 6);
  int lane = threadIdx.x & 63;
  const float* p = x + (size_t)row * WW;
  float s = p[lane] + p[lane + 64] + p[lane + 128] + p[lane + 192] + p[lane + 256];
  for (int off = 32; off; off >>= 1) s += __shfl_down(s, off);
  if (lane == 0) xrow[row] = s * (1.f / (float)WW);
}

__global__ void colmean_kernel(const float* __restrict__ x,
                               float* __restrict__ xcol) {
  int bc = blockIdx.x;
  int w = threadIdx.x;
  const float* p = x + (size_t)bc * HWP;
  float s = 0.f;
  for (int h = 0; h < HH; ++h) s += p[h * WW + w];
  xcol[bc * WW + w] = s * (1.f / (float)HH);
}

// ---------------------------------------------------------------------------
// pool: qpool = q_w @ xrow + q_b ; kpool = k_w @ xcol + k_b
// ---------------------------------------------------------------------------
__global__ __launch_bounds__(256) void pool_kernel(
    const float* __restrict__ xrow, const float* __restrict__ xcol,
    const float* __restrict__ qw, const float* __restrict__ qb,
    const float* __restrict__ kw, const float* __restrict__ kb,
    float* __restrict__ qpool, float* __restrict__ kpool) {
  int gid = blockIdx.x * 256 + threadIdx.x;
  if (gid < 4 * 64 * HH) {
    int b = gid / (64 * HH);
    int c = (gid / HH) & 63;
    int h = gid - (gid / HH) * HH;
    float s = qb[c];
    const float* xr = xrow + (size_t)(b * 64) * HH + h;
    for (int c2 = 0; c2 < 64; ++c2) s = fmaf(qw[c * 64 + c2], xr[c2 * HH], s);
    qpool[gid] = s;
  } else {
    int g2 = gid - 4 * 64 * HH;
    int b = g2 / (64 * WW);
    int c = (g2 / WW) & 63;
    int w = g2 - (g2 / WW) * WW;
    float s = kb[c];
    const float* xc = xcol + (size_t)(b * 64) * WW + w;
    for (int c2 = 0; c2 < 64; ++c2) s = fmaf(kw[c * 64 + c2], xc[c2 * WW], s);
    kpool[g2] = s;
  }
}

// ---------------------------------------------------------------------------
// mz: per (b,c): exact max of rank-1 energy; Z = sum exp(e-M); coef = gamma/Z
// ---------------------------------------------------------------------------
__global__ __launch_bounds__(256) void mz_kernel(
    const float* __restrict__ qpool, const float* __restrict__ kpool,
    const float* __restrict__ pam_gamma, float* __restrict__ Mbuf,
    float* __restrict__ coefb) {
  int bc = blockIdx.x;
  __shared__ float qs[HH];
  __shared__ float ks[WW];
  __shared__ float red[4][4];
  __shared__ float zred[4];
  __shared__ float sM;
  int t = threadIdx.x;
  for (int i = t; i < HH; i += 256) qs[i] = qpool[bc * HH + i];
  for (int i = t; i < WW; i += 256) ks[i] = kpool[bc * WW + i];
  __syncthreads();
  float mq = -1e30f, nq = 1e30f, mk = -1e30f, nk = 1e30f;
  for (int i = t; i < HH; i += 256) {
    float v = qs[i]; mq = fmaxf(mq, v); nq = fminf(nq, v);
  }
  for (int i = t; i < WW; i += 256) {
    float v = ks[i]; mk = fmaxf(mk, v); nk = fminf(nk, v);
  }
  for (int off = 32; off; off >>= 1) {
    mq = fmaxf(mq, __shfl_down(mq, off));
    nq = fminf(nq, __shfl_down(nq, off));
    mk = fmaxf(mk, __shfl_down(mk, off));
    nk = fminf(nk, __shfl_down(nk, off));
  }
  int wid = t >> 6, lane = t & 63;
  if (lane == 0) { red[wid][0] = mq; red[wid][1] = nq; red[wid][2] = mk; red[wid][3] = nk; }
  __syncthreads();
  if (t == 0) {
    mq = red[0][0]; nq = red[0][1]; mk = red[0][2]; nk = red[0][3];
    for (int wv = 1; wv < 4; ++wv) {
      mq = fmaxf(mq, red[wv][0]); nq = fminf(nq, red[wv][1]);
      mk = fmaxf(mk, red[wv][2]); nk = fminf(nk, red[wv][3]);
    }
    sM = fmaxf(fmaxf(mq * mk, mq * nk), fmaxf(nq * mk, nq * nk));
  }
  __syncthreads();
  float M = sM;
  float z = 0.f;
  for (int h = 0; h < HH; ++h) {
    float qv = qs[h];
    for (int w = t; w < WW; w += 256) z += __expf(qv * ks[w] - M);
  }
  for (int off = 32; off; off >>= 1) z += __shfl_down(z, off);
  if (lane == 0) zred[wid] = z;
  __syncthreads();
  if (t == 0) {
    float Z = zred[0] + zred[1] + zred[2] + zred[3];
    Mbuf[bc] = M;
    coefb[bc] = pam_gamma[0] / Z;
  }
}

// ---------------------------------------------------------------------------
extern "C" void kernel_launch(void* const* d_in, const int* in_sizes, int n_in,
                              void* d_out, int out_size, void* d_ws,
                              size_t ws_size, hipStream_t stream) {
  const float* lidar    = (const float*)d_in[0];
  const float* guidance = (const float*)d_in[1];
  const float* illu     = (const float*)d_in[2];
  const float* conv_w   = (const float*)d_in[3];
  const float* tw       = (const float*)d_in[4];
  const float* tb       = (const float*)d_in[5];
  const float* tg       = (const float*)d_in[6];
  const float* tbeta    = (const float*)d_in[7];
  const float* tm       = (const float*)d_in[8];
  const float* tv       = (const float*)d_in[9];
  const float* rgbd_w   = (const float*)d_in[10];
  const float* rgbd_b   = (const float*)d_in[11];
  const float* bnr_g    = (const float*)d_in[12];
  const float* bnr_b    = (const float*)d_in[13];
  const float* bnr_m    = (const float*)d_in[14];
  const float* bnr_v    = (const float*)d_in[15];
  const float* q_w      = (const float*)d_in[16];
  const float* q_b      = (const float*)d_in[17];
  const float* k_w      = (const float*)d_in[18];
  const float* k_b      = (const float*)d_in[19];
  const float* v_w      = (const float*)d_in[20];
  const float* v_b      = (const float*)d_in[21];
  const float* pgm      = (const float*)d_in[22];
  const float* theta    = (const float*)d_in[23];

  char* W = (char*)d_ws;
  float* bufA = (float*)W;                                   // 52,428,800 B
  unsigned short* cat16 = (unsigned short*)(W + 52428800);   // 52,428,800 B
  unsigned short* g16 = cat16;  // alias: g16 dead before cat16 ch2/3 written
  unsigned short* D16 = (unsigned short*)(W + 104857600);    // 26,214,400 B
  char* zeropad = W + 131072000;                             // 4096 B
  float* gate_part = (float*)(W + 131076096);                // 640 f
  float* s_buf = gate_part + 640;                            // 64 f
  float* kd    = s_buf + 64;                                 // 4096 f
  float* xrow  = kd + 4096;                                  // 40960 f
  float* xcol  = xrow + 40960;                               // 81920 f
  float* qpool = xcol + 81920;                               // 40960 f
  float* kpool = qpool + 40960;                              // 81920 f
  float* Mbuf  = kpool + 81920;                              // 256 f
  float* coefb = Mbuf + 256;                                 // 256 f
  short* wpk1  = (short*)(coefb + 256);                      // 73728 s
  short* wpk2  = wpk1 + 73728;                               // 147456 s

  hipMemsetAsync(zeropad, 0, 4096, stream);

  wpack_kernel<<<864, 256, 0, stream>>>(conv_w, rgbd_w, wpk1, wpk2);
  gate_kernel<<<64, 256, 0, stream>>>(illu, tw, tb, tg, tbeta, tm, tv,
                                      gate_part);
  prep_kernel<<<17, 256, 0, stream>>>(gate_part, conv_w, s_buf, kd);

  // guidance -> f16 NHWC (g16, NCHD=2)
  cvt_kernel<<<dim3(200, 4), 256, 0, stream>>>(guidance, g16, 2, 0);

  // ON = conv3x3(guidance)
  convmfma_kernel<2, false><<<dim3(200, 1, 4), 256, 0, stream>>>(
      g16, wpk1, zeropad, nullptr, nullptr, nullptr, nullptr, nullptr, bufA);

  // D = kd @ ON (1x1) -> f16 planar
  pointwise_kernel<true, 0, true><<<dim3(800, 4), 256, 0, stream>>>(
      bufA, kd, nullptr, nullptr, nullptr, nullptr, nullptr, D16);

  // lidar -> cat16 chunks 2,3 (after conv1: overwrites g16 alias region)
  cvt_kernel<<<dim3(200, 4), 256, 0, stream>>>(lidar, cat16, 4, 2);

  // NN -> cat16 chunks 0,1 (fused shift + f16 NHWC convert)
  shift_cvt_kernel<<<dim3(200, 4), 256, 0, stream>>>(bufA, D16, s_buf, theta,
                                                     cat16);

  // x = relu(bn(conv3x3(cat(NN, lidar)))) -> bufA
  convmfma_kernel<4, true><<<dim3(200, 1, 4), 256, 0, stream>>>(
      cat16, wpk2, zeropad, rgbd_b, bnr_g, bnr_b, bnr_m, bnr_v, bufA);

  rowmean_kernel<<<10240, 256, 0, stream>>>(bufA, xrow);
  colmean_kernel<<<256, 320, 0, stream>>>(bufA, xcol);
  pool_kernel<<<480, 256, 0, stream>>>(xrow, xcol, q_w, q_b, k_w, k_b, qpool,
                                       kpool);
  mz_kernel<<<256, 256, 0, stream>>>(qpool, kpool, pgm, Mbuf, coefb);

  // out = coef*exp(qh*kw - M)*(v_w@x + v_b) + x
  pointwise_kernel<false, 1, false><<<dim3(800, 4), 256, 0, stream>>>(
      bufA, v_w, v_b, qpool, kpool, Mbuf, coefb, d_out);
}